// Round 1
// baseline (468.021 us; speedup 1.0000x reference)
//
#include <hip/hip_runtime.h>
#include <math.h>

// Problem constants (from reference): B,V,C,D,H,W = 2,2,32,48,128,160
#define BB 2
#define VV 2
#define CC 32
#define DD 48
#define HH 128
#define WW 160
#define HWPIX (HH*WW)   // 20480

// ---------------- Kernel 1: prep ----------------
// blocks [0,320): transpose src_feas (V,B,C,H,W) -> srcT (V,B,HW,C)
// blocks [320,480): nc_mean output
// block 480: projection matrices (rot/trans per (v,b))

__device__ void inv4x4(const float* A, float* Ainv) {
    float M[4][8];
    for (int r = 0; r < 4; ++r) {
        for (int c = 0; c < 4; ++c) { M[r][c] = A[r*4+c]; M[r][c+4] = (r == c) ? 1.f : 0.f; }
    }
    for (int col = 0; col < 4; ++col) {
        int piv = col; float best = fabsf(M[col][col]);
        for (int r = col+1; r < 4; ++r) { float v = fabsf(M[r][col]); if (v > best) { best = v; piv = r; } }
        if (piv != col) {
            for (int c = 0; c < 8; ++c) { float tmp = M[col][c]; M[col][c] = M[piv][c]; M[piv][c] = tmp; }
        }
        float d = 1.0f / M[col][col];
        for (int c = 0; c < 8; ++c) M[col][c] *= d;
        for (int r = 0; r < 4; ++r) {
            if (r == col) continue;
            float f = M[r][col];
            for (int c = 0; c < 8; ++c) M[r][c] -= f * M[col][c];
        }
    }
    for (int r = 0; r < 4; ++r)
        for (int c = 0; c < 4; ++c) Ainv[r*4+c] = M[r][c+4];
}

__global__ __launch_bounds__(256) void k_prep(
    const float* __restrict__ src,        // (V,B,C,H,W)
    float* __restrict__ srcT,             // (V,B,HW,C)
    const float* __restrict__ projm,      // (B,V+1,2,4,4)
    float* __restrict__ rotv,             // (V*B, 12)
    const float* __restrict__ ref_nc_sum, // (B,1,H,W)
    const float* __restrict__ src_nc_sums,// (V,B,1,H,W)
    float* __restrict__ nc_out)           // (B,H,W) -> d_out tail
{
    int bid = blockIdx.x;
    int tid = threadIdx.x;
    const int NBT = (VV*BB*HWPIX)/256;   // 320
    const int NBN = (BB*HWPIX)/256;      // 160
    if (bid < NBT) {
        int gid = bid*256 + tid;
        int pix = gid % HWPIX;
        int vb  = gid / HWPIX;
        const float* s = src + (size_t)vb*CC*HWPIX + pix;
        float4* dst = (float4*)(srcT + (size_t)vb*HWPIX*CC + (size_t)pix*CC);
        #pragma unroll
        for (int q = 0; q < CC/4; ++q) {
            float4 f;
            f.x = s[(size_t)(4*q+0)*HWPIX];
            f.y = s[(size_t)(4*q+1)*HWPIX];
            f.z = s[(size_t)(4*q+2)*HWPIX];
            f.w = s[(size_t)(4*q+3)*HWPIX];
            dst[q] = f;
        }
    } else if (bid < NBT + NBN) {
        int gid = (bid - NBT)*256 + tid;   // over B*HW
        float s = 0.f;
        float rn = ref_nc_sum[gid];
        #pragma unroll
        for (int v = 0; v < VV; ++v)
            s += (rn + src_nc_sums[(size_t)v*BB*HWPIX + gid]) * 0.5f;
        nc_out[gid] = s / (float)VV;
    } else {
        if (tid < VV*BB) {
            int vb = tid;
            int v = vb / BB;
            int b = vb % BB;
            // ref_proj_new
            const float* E = projm + ((size_t)(b*(VV+1) + 0)*2 + 0)*16;
            const float* K = projm + ((size_t)(b*(VV+1) + 0)*2 + 1)*16;
            float refN[16];
            for (int r = 0; r < 3; ++r)
                for (int c = 0; c < 4; ++c)
                    refN[r*4+c] = K[r*4+0]*E[0*4+c] + K[r*4+1]*E[1*4+c] + K[r*4+2]*E[2*4+c];
            for (int c = 0; c < 4; ++c) refN[12+c] = E[12+c];
            // src_proj_new (view v+1)
            const float* Es = projm + ((size_t)(b*(VV+1) + (v+1))*2 + 0)*16;
            const float* Ks = projm + ((size_t)(b*(VV+1) + (v+1))*2 + 1)*16;
            float srcN[16];
            for (int r = 0; r < 3; ++r)
                for (int c = 0; c < 4; ++c)
                    srcN[r*4+c] = Ks[r*4+0]*Es[0*4+c] + Ks[r*4+1]*Es[1*4+c] + Ks[r*4+2]*Es[2*4+c];
            for (int c = 0; c < 4; ++c) srcN[12+c] = Es[12+c];
            float refI[16];
            inv4x4(refN, refI);
            // P = srcN @ refI
            float P[16];
            for (int r = 0; r < 4; ++r)
                for (int c = 0; c < 4; ++c) {
                    float a = 0.f;
                    for (int k = 0; k < 4; ++k) a += srcN[r*4+k]*refI[k*4+c];
                    P[r*4+c] = a;
                }
            float* o = rotv + vb*12;
            o[0]=P[0]; o[1]=P[1]; o[2]=P[2];
            o[3]=P[4]; o[4]=P[5]; o[5]=P[6];
            o[6]=P[8]; o[7]=P[9]; o[8]=P[10];
            o[9]=P[3]; o[10]=P[7]; o[11]=P[11];
        }
    }
}

// ---------------- Kernel 2: warp + channel contraction ----------------
// one thread per (v,b,pixel); loops D depths; writes t (V,B,D,HW) and entropy (V,B,HW)

__global__ __launch_bounds__(256) void k_warp(
    const float* __restrict__ srcT,   // (V,B,HW,C)
    const float* __restrict__ refF,   // (B,C,H,W)
    const float* __restrict__ regw,   // (C)
    const float* __restrict__ depthv, // (B,D,H,W)
    const float* __restrict__ rotv,   // (V*B,12)
    float* __restrict__ tout,         // (V,B,D,HW)
    float* __restrict__ entout)       // (V,B,HW)
{
    int gid = blockIdx.x*256 + threadIdx.x;   // over V*B*HW
    int pix = gid % HWPIX;
    int vb  = gid / HWPIX;
    int b   = vb % BB;
    float fx = (float)(pix % WW);
    float fy = (float)(pix / WW);

    const float* R = rotv + vb*12;
    float rx = R[0]*fx + R[1]*fy + R[2];
    float ry = R[3]*fx + R[4]*fy + R[5];
    float rz = R[6]*fx + R[7]*fy + R[8];
    float tx = R[9], ty = R[10], tz = R[11];

    float rf[CC], gf[CC];
    const float* rp = refF + (size_t)b*CC*HWPIX + pix;
    #pragma unroll
    for (int c = 0; c < CC; ++c) {
        rf[c] = rp[(size_t)c*HWPIX];
        gf[c] = rf[c] * regw[c];
    }

    const float* sb = srcT + (size_t)vb*HWPIX*CC;
    const float* dv = depthv + (size_t)b*DD*HWPIX + pix;
    float* tp = tout + (size_t)vb*DD*HWPIX + pix;

    float m = -INFINITY, Zs = 0.f, S1 = 0.f;
    #pragma unroll 2
    for (int d = 0; d < DD; ++d) {
        float dep = dv[(size_t)d*HWPIX];
        float X  = fmaf(rx, dep, tx);
        float Y  = fmaf(ry, dep, ty);
        float Zc = fmaf(rz, dep, tz);
        float z  = (fabsf(Zc) < 1e-6f) ? 1e-6f : Zc;
        float iz = 1.0f / z;
        float px = X * iz;
        float py = Y * iz;
        float x0f = floorf(px), y0f = floorf(py);
        float wx = px - x0f, wy = py - y0f;
        int x0 = (int)x0f, y0 = (int)y0f;
        int x1 = x0 + 1, y1 = y0 + 1;
        float v00 = (x0 >= 0 && x0 < WW && y0 >= 0 && y0 < HH) ? 1.f : 0.f;
        float v01 = (x1 >= 0 && x1 < WW && y0 >= 0 && y0 < HH) ? 1.f : 0.f;
        float v10 = (x0 >= 0 && x0 < WW && y1 >= 0 && y1 < HH) ? 1.f : 0.f;
        float v11 = (x1 >= 0 && x1 < WW && y1 >= 0 && y1 < HH) ? 1.f : 0.f;
        float w00 = (1.f-wx)*(1.f-wy)*v00;
        float w01 = wx*(1.f-wy)*v01;
        float w10 = (1.f-wx)*wy*v10;
        float w11 = wx*wy*v11;
        int xc0 = min(max(x0, 0), WW-1), xc1 = min(max(x1, 0), WW-1);
        int yc0 = min(max(y0, 0), HH-1), yc1 = min(max(y1, 0), HH-1);
        const float4* p00 = (const float4*)(sb + ((size_t)yc0*WW + xc0)*CC);
        const float4* p01 = (const float4*)(sb + ((size_t)yc0*WW + xc1)*CC);
        const float4* p10 = (const float4*)(sb + ((size_t)yc1*WW + xc0)*CC);
        const float4* p11 = (const float4*)(sb + ((size_t)yc1*WW + xc1)*CC);
        float s = 0.f, t = 0.f;
        #pragma unroll
        for (int q = 0; q < CC/4; ++q) {
            float4 f00 = p00[q], f01 = p01[q], f10 = p10[q], f11 = p11[q];
            float m0 = w00*f00.x + w01*f01.x + w10*f10.x + w11*f11.x;
            float m1 = w00*f00.y + w01*f01.y + w10*f10.y + w11*f11.y;
            float m2 = w00*f00.z + w01*f01.z + w10*f10.z + w11*f11.z;
            float m3 = w00*f00.w + w01*f01.w + w10*f10.w + w11*f11.w;
            s = fmaf(m0, rf[4*q+0], s);  t = fmaf(m0, gf[4*q+0], t);
            s = fmaf(m1, rf[4*q+1], s);  t = fmaf(m1, gf[4*q+1], t);
            s = fmaf(m2, rf[4*q+2], s);  t = fmaf(m2, gf[4*q+2], t);
            s = fmaf(m3, rf[4*q+3], s);  t = fmaf(m3, gf[4*q+3], t);
        }
        tp[(size_t)d*HWPIX] = t;
        // online softmax stats for entropy
        float mn = fmaxf(m, s);
        float aold = __expf(m - mn);
        float e    = __expf(s - mn);
        Zs = fmaf(Zs, aold, e);
        S1 = fmaf(S1, aold, s*e);
        m = mn;
    }
    // entropy = m + log(Z) - S1/Z
    entout[(size_t)vb*HWPIX + pix] = m + __logf(Zs) - S1/Zs;
}

// ---------------- Kernel 3: conv(vis) + combine + softmax + depth/conf ----------------

__global__ __launch_bounds__(128) void k_final(
    const float* __restrict__ tbuf,   // (V,B,D,HW)
    const float* __restrict__ entbuf, // (V,B,HW)
    const float* __restrict__ ref_nc, // (B,1,H,W)
    const float* __restrict__ w1,     // (32,2,3,3)
    const float* __restrict__ gamma,  // (32)
    const float* __restrict__ beta,   // (32)
    const float* __restrict__ w2,     // (1,32,1,1)
    const float* __restrict__ b2,     // (1)
    const float* __restrict__ regb,   // (1)
    const float* __restrict__ depthv, // (B,D,H,W)
    float* __restrict__ dout)         // depth at 0, conf at B*HW
{
    __shared__ float sw1[576];
    __shared__ float sscale[32], sbeta[32], sw2[32];
    for (int i = threadIdx.x; i < 576; i += 128) sw1[i] = w1[i];
    if (threadIdx.x < 32) {
        sscale[threadIdx.x] = gamma[threadIdx.x] / sqrtf(1.0f + 1e-5f);
        sbeta[threadIdx.x]  = beta[threadIdx.x];
        sw2[threadIdx.x]    = w2[threadIdx.x];
    }
    __syncthreads();
    float bias2 = b2[0], rb = regb[0];

    int gid = blockIdx.x*128 + threadIdx.x;  // over B*HW
    int pix = gid % HWPIX;
    int b   = gid / HWPIX;
    int x = pix % WW, y = pix / WW;

    float vw[VV]; float vwsum = 0.f;
    #pragma unroll
    for (int v = 0; v < VV; ++v) {
        float in0[9], in1[9];
        const float* eb = entbuf + (size_t)(v*BB + b)*HWPIX;
        const float* nb = ref_nc + (size_t)b*HWPIX;
        #pragma unroll
        for (int ky = 0; ky < 3; ++ky) {
            #pragma unroll
            for (int kx = 0; kx < 3; ++kx) {
                int yy = y + ky - 1, xx = x + kx - 1;
                bool ok = (yy >= 0 && yy < HH && xx >= 0 && xx < WW);
                int q = yy*WW + xx;
                in0[ky*3+kx] = ok ? eb[q] : 0.f;
                in1[ky*3+kx] = ok ? nb[q] : 0.f;
            }
        }
        float acc = 0.f;
        #pragma unroll
        for (int o = 0; o < 32; ++o) {
            float a = 0.f;
            #pragma unroll
            for (int k = 0; k < 9; ++k) a = fmaf(sw1[o*18 + k],     in0[k], a);
            #pragma unroll
            for (int k = 0; k < 9; ++k) a = fmaf(sw1[o*18 + 9 + k], in1[k], a);
            a = fmaf(a, sscale[o], sbeta[o]);
            a = fmaxf(a, 0.f);
            acc = fmaf(a, sw2[o], acc);
        }
        float vv = 1.f / (1.f + __expf(-(acc + bias2)));
        vw[v] = vv; vwsum += vv;
    }
    float ivw = 1.f / vwsum;

    float a[DD];
    float mx = -INFINITY;
    #pragma unroll
    for (int d = 0; d < DD; ++d) {
        float num = 0.f;
        #pragma unroll
        for (int v = 0; v < VV; ++v)
            num = fmaf(vw[v], tbuf[((size_t)(v*BB + b)*DD + d)*HWPIX + pix], num);
        float pre = num*ivw + rb;
        a[d] = pre;
        mx = fmaxf(mx, pre);
    }
    float Zs = 0.f, kacc = 0.f, depacc = 0.f;
    const float* dv = depthv + (size_t)b*DD*HWPIX + pix;
    #pragma unroll
    for (int d = 0; d < DD; ++d) {
        float e = __expf(a[d] - mx);
        a[d] = e;
        Zs += e;
        kacc   = fmaf((float)d, e, kacc);
        depacc = fmaf(dv[(size_t)d*HWPIX], e, depacc);
    }
    float iZ = 1.f / Zs;
    float depth = depacc * iZ;
    float didx  = kacc * iZ;
    float r = rintf(didx);                  // round half-to-even, matches jnp.round
    r = fminf(fmaxf(r, 0.f), (float)(DD-1));
    int idx = (int)r;
    float cf = 0.f;
    #pragma unroll
    for (int d = 0; d < DD; ++d)
        cf += (d >= idx-1 && d <= idx+2) ? a[d] : 0.f;
    cf *= iZ;

    dout[(size_t)b*HWPIX + pix] = depth;
    dout[(size_t)BB*HWPIX + (size_t)b*HWPIX + pix] = cf;
}

extern "C" void kernel_launch(void* const* d_in, const int* in_sizes, int n_in,
                              void* d_out, int out_size, void* d_ws, size_t ws_size,
                              hipStream_t stream) {
    const float* ref_fea     = (const float*)d_in[0];
    const float* src_feas    = (const float*)d_in[1];
    const float* ref_nc      = (const float*)d_in[2];
    const float* ref_nc_sum  = (const float*)d_in[3];
    const float* src_nc_sums = (const float*)d_in[4];
    const float* projm       = (const float*)d_in[5];
    const float* depthv      = (const float*)d_in[6];
    const float* w1          = (const float*)d_in[7];
    const float* gamma       = (const float*)d_in[8];
    const float* beta        = (const float*)d_in[9];
    const float* w2          = (const float*)d_in[10];
    const float* b2v         = (const float*)d_in[11];
    const float* regw        = (const float*)d_in[12];
    const float* regb        = (const float*)d_in[13];
    float* out = (float*)d_out;
    float* ws  = (float*)d_ws;

    float* rotv   = ws;                                   // 48 floats (pad to 64)
    float* srcT   = ws + 64;                              // V*B*HW*C = 2,621,440
    float* tbuf   = srcT + (size_t)VV*BB*HWPIX*CC;        // V*B*D*HW = 7,864,320
    float* entbuf = tbuf + (size_t)VV*BB*DD*HWPIX;        // V*B*HW = 81,920

    const int NBT = (VV*BB*HWPIX)/256;   // 320
    const int NBN = (BB*HWPIX)/256;      // 160

    k_prep<<<NBT + NBN + 1, 256, 0, stream>>>(src_feas, srcT, projm, rotv,
                                              ref_nc_sum, src_nc_sums,
                                              out + (size_t)2*BB*HWPIX);
    k_warp<<<(VV*BB*HWPIX)/256, 256, 0, stream>>>(srcT, ref_fea, regw, depthv,
                                                  rotv, tbuf, entbuf);
    k_final<<<(BB*HWPIX)/128, 128, 0, stream>>>(tbuf, entbuf, ref_nc, w1, gamma,
                                                beta, w2, b2v, regb, depthv, out);
}

// Round 2
// 200.941 us; speedup vs baseline: 2.3291x; 2.3291x over previous
//
#include <hip/hip_runtime.h>
#include <math.h>

// Problem constants (from reference): B,V,C,D,H,W = 2,2,32,48,128,160
#define BB 2
#define VV 2
#define CC 32
#define DD 48
#define HH 128
#define WW 160
#define HWPIX (HH*WW)   // 20480

// ---------------- Kernel 1: prep ----------------
// region 1: transpose src_feas (V,B,C,H,W) -> srcT (V,B,HW,C)   [V*B*HW*4 threads]
// region 2: transpose ref_fea  (B,C,H,W)   -> refT (B,HW,C)     [B*HW*4 threads]
// region 3: nc_mean output                                      [B*HW threads]
// region 4: projection matrices (rot/trans per (v,b))           [1 block]

__device__ void inv4x4(const float* A, float* Ainv) {
    float M[4][8];
    for (int r = 0; r < 4; ++r) {
        for (int c = 0; c < 4; ++c) { M[r][c] = A[r*4+c]; M[r][c+4] = (r == c) ? 1.f : 0.f; }
    }
    for (int col = 0; col < 4; ++col) {
        int piv = col; float best = fabsf(M[col][col]);
        for (int r = col+1; r < 4; ++r) { float v = fabsf(M[r][col]); if (v > best) { best = v; piv = r; } }
        if (piv != col) {
            for (int c = 0; c < 8; ++c) { float tmp = M[col][c]; M[col][c] = M[piv][c]; M[piv][c] = tmp; }
        }
        float d = 1.0f / M[col][col];
        for (int c = 0; c < 8; ++c) M[col][c] *= d;
        for (int r = 0; r < 4; ++r) {
            if (r == col) continue;
            float f = M[r][col];
            for (int c = 0; c < 8; ++c) M[r][c] -= f * M[col][c];
        }
    }
    for (int r = 0; r < 4; ++r)
        for (int c = 0; c < 4; ++c) Ainv[r*4+c] = M[r][c+4];
}

__global__ __launch_bounds__(256) void k_prep(
    const float* __restrict__ src,        // (V,B,C,H,W)
    float* __restrict__ srcT,             // (V,B,HW,C)
    const float* __restrict__ refF,       // (B,C,H,W)
    float* __restrict__ refT,             // (B,HW,C)
    const float* __restrict__ projm,      // (B,V+1,2,4,4)
    float* __restrict__ rotv,             // (V*B, 12)
    const float* __restrict__ ref_nc_sum, // (B,1,H,W)
    const float* __restrict__ src_nc_sums,// (V,B,1,H,W)
    float* __restrict__ nc_out)           // (B,H,W) -> d_out tail
{
    const int NB1 = (VV*BB*HWPIX*4)/256;   // 1280
    const int NB2 = (BB*HWPIX*4)/256;      // 640
    const int NB3 = (BB*HWPIX)/256;        // 160
    int bid = blockIdx.x;
    int tid = threadIdx.x;
    if (bid < NB1) {
        int t0 = bid*256 + tid;            // over V*B*4*HW, pix fastest
        int pix = t0 % HWPIX;
        int r   = t0 / HWPIX;
        int sub = r & 3;                   // channel-octet
        int vb  = r >> 2;
        const float* s = src + (size_t)vb*CC*HWPIX + (size_t)sub*8*HWPIX + pix;
        float4* dst = (float4*)(srcT + ((size_t)vb*HWPIX + pix)*CC + sub*8);
        float4 f0, f1;
        f0.x = s[0];              f0.y = s[(size_t)1*HWPIX];
        f0.z = s[(size_t)2*HWPIX];f0.w = s[(size_t)3*HWPIX];
        f1.x = s[(size_t)4*HWPIX];f1.y = s[(size_t)5*HWPIX];
        f1.z = s[(size_t)6*HWPIX];f1.w = s[(size_t)7*HWPIX];
        dst[0] = f0; dst[1] = f1;
    } else if (bid < NB1 + NB2) {
        int t0 = (bid - NB1)*256 + tid;    // over B*4*HW
        int pix = t0 % HWPIX;
        int r   = t0 / HWPIX;
        int sub = r & 3;
        int b   = r >> 2;
        const float* s = refF + (size_t)b*CC*HWPIX + (size_t)sub*8*HWPIX + pix;
        float4* dst = (float4*)(refT + ((size_t)b*HWPIX + pix)*CC + sub*8);
        float4 f0, f1;
        f0.x = s[0];              f0.y = s[(size_t)1*HWPIX];
        f0.z = s[(size_t)2*HWPIX];f0.w = s[(size_t)3*HWPIX];
        f1.x = s[(size_t)4*HWPIX];f1.y = s[(size_t)5*HWPIX];
        f1.z = s[(size_t)6*HWPIX];f1.w = s[(size_t)7*HWPIX];
        dst[0] = f0; dst[1] = f1;
    } else if (bid < NB1 + NB2 + NB3) {
        int gid = (bid - NB1 - NB2)*256 + tid;   // over B*HW
        float s = 0.f;
        float rn = ref_nc_sum[gid];
        #pragma unroll
        for (int v = 0; v < VV; ++v)
            s += (rn + src_nc_sums[(size_t)v*BB*HWPIX + gid]) * 0.5f;
        nc_out[gid] = s / (float)VV;
    } else {
        if (tid < VV*BB) {
            int vb = tid;
            int v = vb / BB;
            int b = vb % BB;
            const float* E = projm + ((size_t)(b*(VV+1) + 0)*2 + 0)*16;
            const float* K = projm + ((size_t)(b*(VV+1) + 0)*2 + 1)*16;
            float refN[16];
            for (int r = 0; r < 3; ++r)
                for (int c = 0; c < 4; ++c)
                    refN[r*4+c] = K[r*4+0]*E[0*4+c] + K[r*4+1]*E[1*4+c] + K[r*4+2]*E[2*4+c];
            for (int c = 0; c < 4; ++c) refN[12+c] = E[12+c];
            const float* Es = projm + ((size_t)(b*(VV+1) + (v+1))*2 + 0)*16;
            const float* Ks = projm + ((size_t)(b*(VV+1) + (v+1))*2 + 1)*16;
            float srcN[16];
            for (int r = 0; r < 3; ++r)
                for (int c = 0; c < 4; ++c)
                    srcN[r*4+c] = Ks[r*4+0]*Es[0*4+c] + Ks[r*4+1]*Es[1*4+c] + Ks[r*4+2]*Es[2*4+c];
            for (int c = 0; c < 4; ++c) srcN[12+c] = Es[12+c];
            float refI[16];
            inv4x4(refN, refI);
            float P[16];
            for (int r = 0; r < 4; ++r)
                for (int c = 0; c < 4; ++c) {
                    float a = 0.f;
                    for (int k = 0; k < 4; ++k) a += srcN[r*4+k]*refI[k*4+c];
                    P[r*4+c] = a;
                }
            float* o = rotv + vb*12;
            o[0]=P[0]; o[1]=P[1]; o[2]=P[2];
            o[3]=P[4]; o[4]=P[5]; o[5]=P[6];
            o[6]=P[8]; o[7]=P[9]; o[8]=P[10];
            o[9]=P[3]; o[10]=P[7]; o[11]=P[11];
        }
    }
}

// ---------------- Kernel 2: warp + channel contraction ----------------
// 8 lanes per (v,b,pixel); lane `sub` owns channels [4*sub,4*sub+4).
// Loops D depths; tree-reduce sim/t across the 8 lanes each depth.

__global__ __launch_bounds__(256, 6) void k_warp(
    const float* __restrict__ srcT,   // (V,B,HW,C)
    const float* __restrict__ refT,   // (B,HW,C)
    const float* __restrict__ regw,   // (C)
    const float* __restrict__ depthv, // (B,D,H,W)
    const float* __restrict__ rotv,   // (V*B,12)
    float* __restrict__ tout,         // (V,B,D,HW)
    float* __restrict__ entout)       // (V,B,HW)
{
    int gid = blockIdx.x*256 + threadIdx.x;   // over V*B*HW*8
    int sub = gid & 7;
    int gp  = gid >> 3;
    int pix = gp % HWPIX;
    int vb  = gp / HWPIX;
    int b   = vb % BB;
    float fx = (float)(pix % WW);
    float fy = (float)(pix / WW);

    const float* R = rotv + vb*12;
    float rx = R[0]*fx + R[1]*fy + R[2];
    float ry = R[3]*fx + R[4]*fy + R[5];
    float rz = R[6]*fx + R[7]*fy + R[8];
    float tx = R[9], ty = R[10], tz = R[11];

    float4 rfv = *(const float4*)(refT + ((size_t)b*HWPIX + pix)*CC + 4*sub);
    float4 rw  = *(const float4*)(regw + 4*sub);
    float4 gfv = make_float4(rfv.x*rw.x, rfv.y*rw.y, rfv.z*rw.z, rfv.w*rw.w);

    const float4* sb4 = (const float4*)(srcT + (size_t)vb*HWPIX*CC);  // [(y*W+x)*8 + q]
    const float* dv = depthv + (size_t)b*DD*HWPIX + pix;
    float* tp = tout + (size_t)vb*DD*HWPIX + pix;

    float m = -INFINITY, Zs = 0.f, S1 = 0.f;
    for (int d = 0; d < DD; ++d) {
        float dep = dv[(size_t)d*HWPIX];
        float X  = fmaf(rx, dep, tx);
        float Y  = fmaf(ry, dep, ty);
        float Zc = fmaf(rz, dep, tz);
        float z  = (fabsf(Zc) < 1e-6f) ? 1e-6f : Zc;
        float iz = 1.0f / z;
        float px = X * iz;
        float py = Y * iz;
        float x0f = floorf(px), y0f = floorf(py);
        float wx = px - x0f, wy = py - y0f;
        int x0 = (int)x0f, y0 = (int)y0f;
        int x1 = x0 + 1, y1 = y0 + 1;
        float v00 = (x0 >= 0 && x0 < WW && y0 >= 0 && y0 < HH) ? 1.f : 0.f;
        float v01 = (x1 >= 0 && x1 < WW && y0 >= 0 && y0 < HH) ? 1.f : 0.f;
        float v10 = (x0 >= 0 && x0 < WW && y1 >= 0 && y1 < HH) ? 1.f : 0.f;
        float v11 = (x1 >= 0 && x1 < WW && y1 >= 0 && y1 < HH) ? 1.f : 0.f;
        float w00 = (1.f-wx)*(1.f-wy)*v00;
        float w01 = wx*(1.f-wy)*v01;
        float w10 = (1.f-wx)*wy*v10;
        float w11 = wx*wy*v11;
        int xc0 = min(max(x0, 0), WW-1), xc1 = min(max(x1, 0), WW-1);
        int yc0 = min(max(y0, 0), HH-1), yc1 = min(max(y1, 0), HH-1);
        int r0 = yc0*WW*8, r1 = yc1*WW*8;
        int c0 = xc0*8 + sub, c1 = xc1*8 + sub;
        float4 f00 = sb4[r0 + c0];
        float4 f01 = sb4[r0 + c1];
        float4 f10 = sb4[r1 + c0];
        float4 f11 = sb4[r1 + c1];
        float m0 = fmaf(w00, f00.x, fmaf(w01, f01.x, fmaf(w10, f10.x, w11*f11.x)));
        float m1 = fmaf(w00, f00.y, fmaf(w01, f01.y, fmaf(w10, f10.y, w11*f11.y)));
        float m2 = fmaf(w00, f00.z, fmaf(w01, f01.z, fmaf(w10, f10.z, w11*f11.z)));
        float m3 = fmaf(w00, f00.w, fmaf(w01, f01.w, fmaf(w10, f10.w, w11*f11.w)));
        float s = fmaf(m0, rfv.x, fmaf(m1, rfv.y, fmaf(m2, rfv.z, m3*rfv.w)));
        float t = fmaf(m0, gfv.x, fmaf(m1, gfv.y, fmaf(m2, gfv.z, m3*gfv.w)));
        // tree-reduce s,t across the 8 sub-lanes (stays within lane group)
        #pragma unroll
        for (int msk = 1; msk < 8; msk <<= 1) {
            s += __shfl_xor(s, msk);
            t += __shfl_xor(t, msk);
        }
        if (sub == 0) tp[(size_t)d*HWPIX] = t;
        // online softmax stats for entropy (redundant in all 8 lanes)
        float mn = fmaxf(m, s);
        float aold = __expf(m - mn);
        float e    = __expf(s - mn);
        Zs = fmaf(Zs, aold, e);
        S1 = fmaf(S1, aold, s*e);
        m = mn;
    }
    if (sub == 0)
        entout[(size_t)vb*HWPIX + pix] = m + __logf(Zs) - S1/Zs;
}

// ---------------- Kernel 3: conv(vis) + combine + softmax + depth/conf ----------------
// 8 lanes per ref pixel: conv outputs split 4/lane, depths split 6/lane.

__global__ __launch_bounds__(256) void k_final(
    const float* __restrict__ tbuf,   // (V,B,D,HW)
    const float* __restrict__ entbuf, // (V,B,HW)
    const float* __restrict__ ref_nc, // (B,1,H,W)
    const float* __restrict__ w1,     // (32,2,3,3)
    const float* __restrict__ gamma,  // (32)
    const float* __restrict__ beta,   // (32)
    const float* __restrict__ w2,     // (1,32,1,1)
    const float* __restrict__ b2,     // (1)
    const float* __restrict__ regb,   // (1)
    const float* __restrict__ depthv, // (B,D,H,W)
    float* __restrict__ dout)         // depth at 0, conf at B*HW
{
    __shared__ float sw1[576];
    __shared__ float sscale[32], sbeta[32], sw2[32];
    for (int i = threadIdx.x; i < 576; i += 256) sw1[i] = w1[i];
    if (threadIdx.x < 32) {
        sscale[threadIdx.x] = gamma[threadIdx.x] / sqrtf(1.0f + 1e-5f);
        sbeta[threadIdx.x]  = beta[threadIdx.x];
        sw2[threadIdx.x]    = w2[threadIdx.x];
    }
    __syncthreads();
    float bias2 = b2[0], rb = regb[0];

    int gid = blockIdx.x*256 + threadIdx.x;  // over B*HW*8
    int sub = gid & 7;
    int gp  = gid >> 3;
    int pix = gp % HWPIX;
    int b   = gp / HWPIX;
    int x = pix % WW, y = pix / WW;

    float vw[VV]; float vwsum = 0.f;
    #pragma unroll
    for (int v = 0; v < VV; ++v) {
        float in0[9], in1[9];
        const float* eb = entbuf + (size_t)(v*BB + b)*HWPIX;
        const float* nb = ref_nc + (size_t)b*HWPIX;
        #pragma unroll
        for (int ky = 0; ky < 3; ++ky) {
            #pragma unroll
            for (int kx = 0; kx < 3; ++kx) {
                int yy = y + ky - 1, xx = x + kx - 1;
                bool ok = (yy >= 0 && yy < HH && xx >= 0 && xx < WW);
                int q = yy*WW + xx;
                in0[ky*3+kx] = ok ? eb[q] : 0.f;
                in1[ky*3+kx] = ok ? nb[q] : 0.f;
            }
        }
        // each lane computes 4 of the 32 hidden channels
        float accp = 0.f;
        #pragma unroll
        for (int j = 0; j < 4; ++j) {
            int o = sub*4 + j;
            float a = 0.f;
            #pragma unroll
            for (int k = 0; k < 9; ++k) a = fmaf(sw1[o*18 + k],     in0[k], a);
            #pragma unroll
            for (int k = 0; k < 9; ++k) a = fmaf(sw1[o*18 + 9 + k], in1[k], a);
            a = fmaf(a, sscale[o], sbeta[o]);
            a = fmaxf(a, 0.f);
            accp = fmaf(a, sw2[o], accp);
        }
        #pragma unroll
        for (int msk = 1; msk < 8; msk <<= 1) accp += __shfl_xor(accp, msk);
        float vv = 1.f / (1.f + expf(-(accp + bias2)));
        vw[v] = vv; vwsum += vv;
    }
    float ivw = 1.f / vwsum;

    // depths d = sub + 8*k, k<6
    float pre[6];
    float mx = -INFINITY;
    #pragma unroll
    for (int k = 0; k < 6; ++k) {
        int d = sub + 8*k;
        float num = 0.f;
        #pragma unroll
        for (int v = 0; v < VV; ++v)
            num = fmaf(vw[v], tbuf[((size_t)(v*BB + b)*DD + d)*HWPIX + pix], num);
        float p = num*ivw + rb;
        pre[k] = p;
        mx = fmaxf(mx, p);
    }
    #pragma unroll
    for (int msk = 1; msk < 8; msk <<= 1) mx = fmaxf(mx, __shfl_xor(mx, msk));

    const float* dv = depthv + (size_t)b*DD*HWPIX + pix;
    float Zp = 0.f, kp = 0.f, dp = 0.f;
    float ev[6];
    #pragma unroll
    for (int k = 0; k < 6; ++k) {
        int d = sub + 8*k;
        float e = expf(pre[k] - mx);
        ev[k] = e;
        Zp += e;
        kp = fmaf((float)d, e, kp);
        dp = fmaf(dv[(size_t)d*HWPIX], e, dp);
    }
    #pragma unroll
    for (int msk = 1; msk < 8; msk <<= 1) {
        Zp += __shfl_xor(Zp, msk);
        kp += __shfl_xor(kp, msk);
        dp += __shfl_xor(dp, msk);
    }
    float iZ = 1.f / Zp;
    float depth = dp * iZ;
    float didx  = kp * iZ;
    float r = rintf(didx);                  // round half-to-even, matches jnp.round
    r = fminf(fmaxf(r, 0.f), (float)(DD-1));
    int idx = (int)r;
    float cfp = 0.f;
    #pragma unroll
    for (int k = 0; k < 6; ++k) {
        int d = sub + 8*k;
        cfp += (d >= idx-1 && d <= idx+2) ? ev[k] : 0.f;
    }
    #pragma unroll
    for (int msk = 1; msk < 8; msk <<= 1) cfp += __shfl_xor(cfp, msk);

    if (sub == 0) {
        dout[(size_t)b*HWPIX + pix] = depth;
        dout[(size_t)BB*HWPIX + (size_t)b*HWPIX + pix] = cfp * iZ;
    }
}

extern "C" void kernel_launch(void* const* d_in, const int* in_sizes, int n_in,
                              void* d_out, int out_size, void* d_ws, size_t ws_size,
                              hipStream_t stream) {
    const float* ref_fea     = (const float*)d_in[0];
    const float* src_feas    = (const float*)d_in[1];
    const float* ref_nc      = (const float*)d_in[2];
    const float* ref_nc_sum  = (const float*)d_in[3];
    const float* src_nc_sums = (const float*)d_in[4];
    const float* projm       = (const float*)d_in[5];
    const float* depthv      = (const float*)d_in[6];
    const float* w1          = (const float*)d_in[7];
    const float* gamma       = (const float*)d_in[8];
    const float* beta        = (const float*)d_in[9];
    const float* w2          = (const float*)d_in[10];
    const float* b2v         = (const float*)d_in[11];
    const float* regw        = (const float*)d_in[12];
    const float* regb        = (const float*)d_in[13];
    float* out = (float*)d_out;
    float* ws  = (float*)d_ws;

    float* rotv   = ws;                                   // 48 floats (pad to 64)
    float* srcT   = ws + 64;                              // V*B*HW*C = 2,621,440
    float* refT   = srcT + (size_t)VV*BB*HWPIX*CC;        // B*HW*C = 1,310,720
    float* tbuf   = refT + (size_t)BB*HWPIX*CC;           // V*B*D*HW = 7,864,320
    float* entbuf = tbuf + (size_t)VV*BB*DD*HWPIX;        // V*B*HW = 81,920

    const int NB1 = (VV*BB*HWPIX*4)/256;   // 1280
    const int NB2 = (BB*HWPIX*4)/256;      // 640
    const int NB3 = (BB*HWPIX)/256;        // 160

    k_prep<<<NB1 + NB2 + NB3 + 1, 256, 0, stream>>>(src_feas, srcT, ref_fea, refT,
                                                    projm, rotv, ref_nc_sum, src_nc_sums,
                                                    out + (size_t)2*BB*HWPIX);
    k_warp<<<(VV*BB*HWPIX*8)/256, 256, 0, stream>>>(srcT, refT, regw, depthv,
                                                    rotv, tbuf, entbuf);
    k_final<<<(BB*HWPIX*8)/256, 256, 0, stream>>>(tbuf, entbuf, ref_nc, w1, gamma,
                                                  beta, w2, b2v, regb, depthv, out);
}